// Round 1
// baseline (318.877 us; speedup 1.0000x reference)
//
#include <hip/hip_runtime.h>
#include <math.h>

#define B_  8
#define T_  2048
#define D_  1024
#define E_  8
#define FF_ 4096
#define N_  64            // B*E rows through the FFN
#define BT_ (B_*T_)

// ---------------------------------------------------------------------------
// K1a: partial logits over a 128-d chunk. grid (BT/256, 8), 256 threads.
// One thread owns ONE token and all 8 experts: x4 is read once per 8 FMA4s,
// wgT reads are wave-uniform broadcasts. part[dc][t][e] += X[t,dchunk]·Wg.
// ---------------------------------------------------------------------------
__global__ __launch_bounds__(256) void k_logits_part(
    const float* __restrict__ X, const float* __restrict__ Wg,
    float* __restrict__ part)
{
    __shared__ float wgT[E_ * 128];      // [e][d_local], 4 KB, read broadcast
    __shared__ float xt[256 * 36];       // 256 tokens x 32 d (pad to 36), 36 KB

    const int tid = threadIdx.x;
    const int bt0 = blockIdx.x * 256;
    const int d0  = blockIdx.y * 128;

    // stage Wg chunk transposed: Wg[(d0+dl)*8+e] -> wgT[e*128+dl] (coalesced read)
    #pragma unroll
    for (int r = 0; r < 4; ++r) {
        int idx = r * 256 + tid;          // idx = dl*8 + e
        wgT[(idx & 7) * 128 + (idx >> 3)] = Wg[(size_t)d0 * E_ + idx];
    }

    float acc[8];
    #pragma unroll
    for (int e = 0; e < 8; ++e) acc[e] = 0.f;

    for (int dt = 0; dt < 4; ++dt) {
        __syncthreads();                  // first iter also covers wgT staging
        #pragma unroll
        for (int r = 0; r < 8; ++r) {
            int fi = r * 256 + tid;       // float4 index = token*8 + dj
            int token = fi >> 3, dj = fi & 7;
            const float4 v = *(const float4*)
                &X[(size_t)(bt0 + token) * D_ + d0 + dt * 32 + dj * 4];
            *(float4*)&xt[token * 36 + dj * 4] = v;   // pad 36: even bank spread
        }
        __syncthreads();
        #pragma unroll
        for (int dj = 0; dj < 8; ++dj) {
            const float4 x4 = *(const float4*)&xt[tid * 36 + dj * 4];
            #pragma unroll
            for (int e = 0; e < 8; ++e) {
                const float4 w4 = *(const float4*)&wgT[e * 128 + dt * 32 + dj * 4];
                acc[e] += x4.x * w4.x + x4.y * w4.y + x4.z * w4.z + x4.w * w4.w;
            }
        }
    }

    float* pp = &part[(size_t)blockIdx.y * BT_ * E_ + (size_t)(bt0 + tid) * E_];
    *(float4*)&pp[0] = make_float4(acc[0], acc[1], acc[2], acc[3]);
    *(float4*)&pp[4] = make_float4(acc[4], acc[5], acc[6], acc[7]);
}

// ---------------------------------------------------------------------------
// K1b: merge 8 d-chunk partials + bg -> logits; per-(b,e) sum of exp via
// block reduction + atomicAdd. grid (BT/256), 256 threads (one token each).
// ---------------------------------------------------------------------------
__global__ __launch_bounds__(256) void k_logits_merge(
    const float* __restrict__ part, const float* __restrict__ bg,
    float* __restrict__ logits, float* __restrict__ sumexp)
{
    __shared__ float red[8 * 256];
    const int tid = threadIdx.x;
    const int token = blockIdx.x * 256 + tid;
    const int b = blockIdx.x >> 3;        // 8 blocks per batch (2048/256)

    float a[8];
    #pragma unroll
    for (int e = 0; e < 8; ++e) a[e] = 0.f;
    #pragma unroll
    for (int p = 0; p < 8; ++p) {
        const float* pp = &part[(size_t)p * BT_ * E_ + (size_t)token * E_];
        const float4 v0 = *(const float4*)&pp[0];
        const float4 v1 = *(const float4*)&pp[4];
        a[0] += v0.x; a[1] += v0.y; a[2] += v0.z; a[3] += v0.w;
        a[4] += v1.x; a[5] += v1.y; a[6] += v1.z; a[7] += v1.w;
    }
    #pragma unroll
    for (int e = 0; e < 8; ++e) a[e] += bg[e];

    float* lp = &logits[(size_t)token * E_];
    *(float4*)&lp[0] = make_float4(a[0], a[1], a[2], a[3]);
    *(float4*)&lp[4] = make_float4(a[4], a[5], a[6], a[7]);

    #pragma unroll
    for (int e = 0; e < 8; ++e) red[e * 256 + tid] = expf(a[e]);
    __syncthreads();
    for (int s = 128; s >= 1; s >>= 1) {
        if (tid < s) {
            #pragma unroll
            for (int e = 0; e < 8; ++e)
                red[e * 256 + tid] += red[e * 256 + tid + s];
        }
        __syncthreads();
    }
    if (tid < 8) atomicAdd(&sumexp[b * E_ + tid], red[tid * 256]);
}

// ---------------------------------------------------------------------------
// K2: slots partials. grid (64 slices of 32 tokens, 8 b), 256 threads.
// Thread owns one d-float4; unroll-8 t-loop keeps 8 b128 loads in flight.
// ---------------------------------------------------------------------------
__global__ __launch_bounds__(256) void k_slots_part(
    const float* __restrict__ X, const float* __restrict__ logits,
    const float* __restrict__ sumexp, float* __restrict__ part)
{
    __shared__ float wlds[32 * 8];
    const int tid = threadIdx.x;
    const int ts = blockIdx.x, b = blockIdx.y;
    const int t0 = ts * 32;

    {
        int t = tid >> 3, e = tid & 7;    // 256 threads = 32 tokens x 8 e
        wlds[tid] = expf(logits[((size_t)b * T_ + t0 + t) * E_ + e])
                    / sumexp[b * E_ + e];
    }
    __syncthreads();

    float4 acc[8];
    #pragma unroll
    for (int e = 0; e < 8; ++e) { acc[e].x = acc[e].y = acc[e].z = acc[e].w = 0.f; }

    const float* xb = &X[((size_t)b * T_ + t0) * D_ + tid * 4];
    #pragma unroll 8
    for (int t = 0; t < 32; ++t) {
        const float4 x4 = *(const float4*)&xb[(size_t)t * D_];
        const float4 wA = *(const float4*)&wlds[t * 8];       // broadcast
        const float4 wB = *(const float4*)&wlds[t * 8 + 4];   // broadcast
        const float w[8] = {wA.x, wA.y, wA.z, wA.w, wB.x, wB.y, wB.z, wB.w};
        #pragma unroll
        for (int e = 0; e < 8; ++e) {
            acc[e].x += x4.x * w[e];
            acc[e].y += x4.y * w[e];
            acc[e].z += x4.z * w[e];
            acc[e].w += x4.w * w[e];
        }
    }
    #pragma unroll
    for (int e = 0; e < 8; ++e) {
        *(float4*)&part[(size_t)ts * (N_ * D_) + (size_t)(b * E_ + e) * D_ + tid * 4] = acc[e];
    }
}

// K3: reduce 64 slot partials -> slots[64][1024]
__global__ __launch_bounds__(256) void k_reduce_slots(
    const float* __restrict__ part, float* __restrict__ slots)
{
    const int i = blockIdx.x * 256 + threadIdx.x;     // 65536
    float s = 0.f;
    #pragma unroll
    for (int p = 0; p < 64; ++p) s += part[(size_t)p * (N_ * D_) + i];
    slots[i] = s;
}

// ---------------------------------------------------------------------------
// K4/K6: k-split GEMM partial, ktile = 64, one f-column per thread.
// part[kc][n][f] = sum_{k in tile} A[n][k] * W[k][f].
// grid (F/256, K/64), 256 threads.
// ---------------------------------------------------------------------------
__global__ __launch_bounds__(256) void k_gemm_part(
    const float* __restrict__ A, const float* __restrict__ W,
    float* __restrict__ part, int K, int F)
{
    __shared__ float sT[64 * 68];                 // [kk][n], pad 68

    const int tid = threadIdx.x;
    const int f0 = blockIdx.x * 256 + tid;
    const int k0 = blockIdx.y * 64;

    #pragma unroll
    for (int r = 0; r < 16; ++r) {                // 4096 elements
        int idx = r * 256 + tid;
        int n = idx >> 6, kk = idx & 63;
        sT[kk * 68 + n] = A[(size_t)n * K + k0 + kk];
    }
    __syncthreads();

    float acc[64];
    #pragma unroll
    for (int n = 0; n < 64; ++n) acc[n] = 0.f;

    #pragma unroll 4
    for (int kk = 0; kk < 64; ++kk) {
        const float w = W[(size_t)(k0 + kk) * F + f0];
        const float4* sp = (const float4*)&sT[kk * 68];   // broadcast reads
        #pragma unroll
        for (int j = 0; j < 16; ++j) {
            const float4 s = sp[j];
            acc[4*j+0] += s.x * w; acc[4*j+1] += s.y * w;
            acc[4*j+2] += s.z * w; acc[4*j+3] += s.w * w;
        }
    }

    const size_t base = (size_t)blockIdx.y * N_ * F;
    #pragma unroll
    for (int n = 0; n < 64; ++n)
        part[base + (size_t)n * F + f0] = acc[n];
}

// K5: reduce 16 GEMM1 partials + b1, SiLU -> h[64][4096]
__global__ __launch_bounds__(256) void k_reduce_silu(
    const float* __restrict__ part, const float* __restrict__ b1,
    float* __restrict__ h)
{
    const int i = blockIdx.x * 256 + threadIdx.x;     // 262144
    float s = 0.f;
    #pragma unroll
    for (int p = 0; p < 16; ++p) s += part[(size_t)p * (N_ * FF_) + i];
    s += b1[i & (FF_ - 1)];
    h[i] = s / (1.f + expf(-s));                      // silu
}

// K7: reduce 64 GEMM2 partials + b2 -> y[64][1024]
__global__ __launch_bounds__(256) void k_reduce_bias(
    const float* __restrict__ part, const float* __restrict__ b2,
    float* __restrict__ y)
{
    const int i = blockIdx.x * 256 + threadIdx.x;     // 65536
    float s = 0.f;
    #pragma unroll
    for (int p = 0; p < 64; ++p) s += part[(size_t)p * (N_ * D_) + i];
    y[i] = s + b2[i & (D_ - 1)];
}

// ---------------------------------------------------------------------------
// K8: out[b][t][d] = sum_e softmax_e(logits[b,t,:])[e] * y[b*8+e][d]
// ---------------------------------------------------------------------------
__global__ __launch_bounds__(256) void k_combine(
    const float* __restrict__ logits, const float* __restrict__ y,
    float* __restrict__ out)
{
    __shared__ float wlds[64 * 8];
    const int tid = threadIdx.x;
    const int dc = blockIdx.x, tc = blockIdx.y, b = blockIdx.z;
    const int t0 = tc * 64;

    if (tid < 64) {
        const float* lp = &logits[((size_t)b * T_ + t0 + tid) * E_];
        float ex[8]; float s = 0.f;
        #pragma unroll
        for (int i = 0; i < 8; ++i) { ex[i] = expf(lp[i]); s += ex[i]; }
        const float invs = 1.f / s;
        #pragma unroll
        for (int i = 0; i < 8; ++i) wlds[tid * 8 + i] = ex[i] * invs;
    }
    __syncthreads();

    const int d = dc * 256 + tid;
    float yv[8];
    #pragma unroll
    for (int e = 0; e < 8; ++e) yv[e] = y[(size_t)(b * E_ + e) * D_ + d];

    for (int t = 0; t < 64; ++t) {
        const float4 wA = *(const float4*)&wlds[t * 8];
        const float4 wB = *(const float4*)&wlds[t * 8 + 4];
        const float acc = wA.x * yv[0] + wA.y * yv[1] + wA.z * yv[2] + wA.w * yv[3]
                        + wB.x * yv[4] + wB.y * yv[5] + wB.z * yv[6] + wB.w * yv[7];
        out[((size_t)b * T_ + t0 + t) * D_ + d] = acc;
    }
}

// ---------------------------------------------------------------------------
extern "C" void kernel_launch(void* const* d_in, const int* in_sizes, int n_in,
                              void* d_out, int out_size, void* d_ws, size_t ws_size,
                              hipStream_t stream)
{
    const float* X  = (const float*)d_in[0];
    const float* Wg = (const float*)d_in[1];
    const float* bg = (const float*)d_in[2];
    const float* W1 = (const float*)d_in[3];
    const float* b1 = (const float*)d_in[4];
    const float* W2 = (const float*)d_in[5];
    const float* b2 = (const float*)d_in[6];
    float* out = (float*)d_out;

    // ws layout (fp32), ~2.0 MB total
    float* wsf    = (float*)d_ws;
    float* logits = wsf;                        // 131072
    float* sumexp = logits + BT_ * E_;          // 64
    float* slots  = sumexp + 64;                // 65536
    float* h      = slots + N_ * D_;            // 262144
    float* y      = h + N_ * FF_;               // 65536

    // Large partial buffers live in d_out (64 MB), fully overwritten by
    // k_combine at the end. Max partial usage = 16 MB.
    float* part = out;

    hipMemsetAsync(sumexp, 0, 64 * sizeof(float), stream);

    hipLaunchKernelGGL(k_logits_part,  dim3(BT_ / 256, 8), dim3(256), 0, stream,
                       X, Wg, part);
    hipLaunchKernelGGL(k_logits_merge, dim3(BT_ / 256),    dim3(256), 0, stream,
                       part, bg, logits, sumexp);
    hipLaunchKernelGGL(k_slots_part,   dim3(64, 8),        dim3(256), 0, stream,
                       X, logits, sumexp, part);
    hipLaunchKernelGGL(k_reduce_slots, dim3(256),          dim3(256), 0, stream,
                       part, slots);
    hipLaunchKernelGGL(k_gemm_part,    dim3(FF_ / 256, 1024 / 64), dim3(256), 0, stream,
                       slots, W1, part, 1024, FF_);
    hipLaunchKernelGGL(k_reduce_silu,  dim3(N_ * FF_ / 256), dim3(256), 0, stream,
                       part, b1, h);
    hipLaunchKernelGGL(k_gemm_part,    dim3(D_ / 256, FF_ / 64), dim3(256), 0, stream,
                       h, W2, part, FF_, D_);
    hipLaunchKernelGGL(k_reduce_bias,  dim3(N_ * D_ / 256), dim3(256), 0, stream,
                       part, b2, y);
    hipLaunchKernelGGL(k_combine,      dim3(4, 32, 8), dim3(256), 0, stream,
                       logits, y, out);
}

// Round 2
// 260.408 us; speedup vs baseline: 1.2245x; 1.2245x over previous
//
#include <hip/hip_runtime.h>
#include <math.h>

#define B_  8
#define T_  2048
#define D_  1024
#define E_  8
#define FF_ 4096
#define N_  64            // B*E rows through the FFN
#define BT_ (B_*T_)

// ---------------------------------------------------------------------------
// K1a: partial logits over a 128-d chunk. grid (BT/256, 8), 256 threads.
// One thread owns ONE token and all 8 experts: x4 is read once per 8 FMA4s,
// wgT reads are wave-uniform broadcasts. part[dc][t][e] += X[t,dchunk]·Wg.
// ---------------------------------------------------------------------------
__global__ __launch_bounds__(256) void k_logits_part(
    const float* __restrict__ X, const float* __restrict__ Wg,
    float* __restrict__ part)
{
    __shared__ float wgT[E_ * 128];      // [e][d_local], 4 KB, read broadcast
    __shared__ float xt[256 * 36];       // 256 tokens x 32 d (pad to 36), 36 KB

    const int tid = threadIdx.x;
    const int bt0 = blockIdx.x * 256;
    const int d0  = blockIdx.y * 128;

    // stage Wg chunk transposed: Wg[(d0+dl)*8+e] -> wgT[e*128+dl] (coalesced read)
    #pragma unroll
    for (int r = 0; r < 4; ++r) {
        int idx = r * 256 + tid;          // idx = dl*8 + e
        wgT[(idx & 7) * 128 + (idx >> 3)] = Wg[(size_t)d0 * E_ + idx];
    }

    float acc[8];
    #pragma unroll
    for (int e = 0; e < 8; ++e) acc[e] = 0.f;

    for (int dt = 0; dt < 4; ++dt) {
        __syncthreads();                  // first iter also covers wgT staging
        #pragma unroll
        for (int r = 0; r < 8; ++r) {
            int fi = r * 256 + tid;       // float4 index = token*8 + dj
            int token = fi >> 3, dj = fi & 7;
            const float4 v = *(const float4*)
                &X[(size_t)(bt0 + token) * D_ + d0 + dt * 32 + dj * 4];
            *(float4*)&xt[token * 36 + dj * 4] = v;   // pad 36: even bank spread
        }
        __syncthreads();
        #pragma unroll
        for (int dj = 0; dj < 8; ++dj) {
            const float4 x4 = *(const float4*)&xt[tid * 36 + dj * 4];
            #pragma unroll
            for (int e = 0; e < 8; ++e) {
                const float4 w4 = *(const float4*)&wgT[e * 128 + dt * 32 + dj * 4];
                acc[e] += x4.x * w4.x + x4.y * w4.y + x4.z * w4.z + x4.w * w4.w;
            }
        }
    }

    float* pp = &part[(size_t)blockIdx.y * BT_ * E_ + (size_t)(bt0 + tid) * E_];
    *(float4*)&pp[0] = make_float4(acc[0], acc[1], acc[2], acc[3]);
    *(float4*)&pp[4] = make_float4(acc[4], acc[5], acc[6], acc[7]);
}

// ---------------------------------------------------------------------------
// K1b: merge 8 d-chunk partials + bg -> logits; per-(b,e) sum of exp via
// block reduction + atomicAdd. grid (BT/256), 256 threads (one token each).
// ---------------------------------------------------------------------------
__global__ __launch_bounds__(256) void k_logits_merge(
    const float* __restrict__ part, const float* __restrict__ bg,
    float* __restrict__ logits, float* __restrict__ sumexp)
{
    __shared__ float red[8 * 256];
    const int tid = threadIdx.x;
    const int token = blockIdx.x * 256 + tid;
    const int b = blockIdx.x >> 3;        // 8 blocks per batch (2048/256)

    float a[8];
    #pragma unroll
    for (int e = 0; e < 8; ++e) a[e] = 0.f;
    #pragma unroll
    for (int p = 0; p < 8; ++p) {
        const float* pp = &part[(size_t)p * BT_ * E_ + (size_t)token * E_];
        const float4 v0 = *(const float4*)&pp[0];
        const float4 v1 = *(const float4*)&pp[4];
        a[0] += v0.x; a[1] += v0.y; a[2] += v0.z; a[3] += v0.w;
        a[4] += v1.x; a[5] += v1.y; a[6] += v1.z; a[7] += v1.w;
    }
    #pragma unroll
    for (int e = 0; e < 8; ++e) a[e] += bg[e];

    float* lp = &logits[(size_t)token * E_];
    *(float4*)&lp[0] = make_float4(a[0], a[1], a[2], a[3]);
    *(float4*)&lp[4] = make_float4(a[4], a[5], a[6], a[7]);

    #pragma unroll
    for (int e = 0; e < 8; ++e) red[e * 256 + tid] = expf(a[e]);
    __syncthreads();
    for (int s = 128; s >= 1; s >>= 1) {
        if (tid < s) {
            #pragma unroll
            for (int e = 0; e < 8; ++e)
                red[e * 256 + tid] += red[e * 256 + tid + s];
        }
        __syncthreads();
    }
    if (tid < 8) atomicAdd(&sumexp[b * E_ + tid], red[tid * 256]);
}

// ---------------------------------------------------------------------------
// K2: slots partials. grid (64 slices of 32 tokens, 8 b), 256 threads.
// Thread owns one d-float4; unroll-8 t-loop keeps 8 b128 loads in flight.
// ---------------------------------------------------------------------------
__global__ __launch_bounds__(256) void k_slots_part(
    const float* __restrict__ X, const float* __restrict__ logits,
    const float* __restrict__ sumexp, float* __restrict__ part)
{
    __shared__ float wlds[32 * 8];
    const int tid = threadIdx.x;
    const int ts = blockIdx.x, b = blockIdx.y;
    const int t0 = ts * 32;

    {
        int t = tid >> 3, e = tid & 7;    // 256 threads = 32 tokens x 8 e
        wlds[tid] = expf(logits[((size_t)b * T_ + t0 + t) * E_ + e])
                    / sumexp[b * E_ + e];
    }
    __syncthreads();

    float4 acc[8];
    #pragma unroll
    for (int e = 0; e < 8; ++e) { acc[e].x = acc[e].y = acc[e].z = acc[e].w = 0.f; }

    const float* xb = &X[((size_t)b * T_ + t0) * D_ + tid * 4];
    #pragma unroll 8
    for (int t = 0; t < 32; ++t) {
        const float4 x4 = *(const float4*)&xb[(size_t)t * D_];
        const float4 wA = *(const float4*)&wlds[t * 8];       // broadcast
        const float4 wB = *(const float4*)&wlds[t * 8 + 4];   // broadcast
        const float w[8] = {wA.x, wA.y, wA.z, wA.w, wB.x, wB.y, wB.z, wB.w};
        #pragma unroll
        for (int e = 0; e < 8; ++e) {
            acc[e].x += x4.x * w[e];
            acc[e].y += x4.y * w[e];
            acc[e].z += x4.z * w[e];
            acc[e].w += x4.w * w[e];
        }
    }
    #pragma unroll
    for (int e = 0; e < 8; ++e) {
        *(float4*)&part[(size_t)ts * (N_ * D_) + (size_t)(b * E_ + e) * D_ + tid * 4] = acc[e];
    }
}

// K3: reduce 64 slot partials -> slots[64][1024]
__global__ __launch_bounds__(256) void k_reduce_slots(
    const float* __restrict__ part, float* __restrict__ slots)
{
    const int i = blockIdx.x * 256 + threadIdx.x;     // 65536
    float s = 0.f;
    #pragma unroll
    for (int p = 0; p < 64; ++p) s += part[(size_t)p * (N_ * D_) + i];
    slots[i] = s;
}

// ---------------------------------------------------------------------------
// K4/K6: k-split GEMM partial, KT=64. part[kc][n][f] = sum_k A[n][k]*W[k][f].
// Block tile 64 rows x 128 cols, 256 threads: thread = (rg = tid>>5 owning
// 8 rows, cg = tid&31 owning 4 cols). acc = 8 x float4 = 32 VGPR (no spill).
// A staged [row][kk] in LDS; inner A-reads are half-wave broadcasts
// (all lanes of a half-wave share rg), W reads are coalesced b128.
// grid (F/128, K/64).
// ---------------------------------------------------------------------------
__global__ __launch_bounds__(256) void k_gemm_part(
    const float* __restrict__ A, const float* __restrict__ W,
    float* __restrict__ part, int K, int F)
{
    __shared__ float As[64][64];                  // 16 KB, [row][kk]

    const int tid = threadIdx.x;
    const int rg  = tid >> 5;                     // 0..7  (8 rows each)
    const int cg  = tid & 31;                     // 0..31 (4 cols each)
    const int f0  = blockIdx.x * 128 + cg * 4;
    const int k0  = blockIdx.y * 64;

    // stage A tile: 64 rows x 64 kk = 1024 float4, 4 per thread, coalesced.
    #pragma unroll
    for (int i = 0; i < 4; ++i) {
        int idx = i * 256 + tid;                  // row = idx>>4, kq = idx&15
        int row = idx >> 4, kq = idx & 15;
        const float4 v = *(const float4*)&A[(size_t)row * K + k0 + kq * 4];
        *(float4*)&As[row][kq * 4] = v;           // 2-way write alias: free
    }
    __syncthreads();

    float4 acc[8];
    #pragma unroll
    for (int r = 0; r < 8; ++r) { acc[r].x = acc[r].y = acc[r].z = acc[r].w = 0.f; }

    #pragma unroll 2
    for (int kq = 0; kq < 16; ++kq) {             // 4 kk per step
        float4 w0 = *(const float4*)&W[(size_t)(k0 + kq * 4 + 0) * F + f0];
        float4 w1 = *(const float4*)&W[(size_t)(k0 + kq * 4 + 1) * F + f0];
        float4 w2 = *(const float4*)&W[(size_t)(k0 + kq * 4 + 2) * F + f0];
        float4 w3 = *(const float4*)&W[(size_t)(k0 + kq * 4 + 3) * F + f0];
        #pragma unroll
        for (int r = 0; r < 8; ++r) {
            const float4 a = *(const float4*)&As[rg * 8 + r][kq * 4];  // broadcast
            acc[r].x += a.x * w0.x + a.y * w1.x + a.z * w2.x + a.w * w3.x;
            acc[r].y += a.x * w0.y + a.y * w1.y + a.z * w2.y + a.w * w3.y;
            acc[r].z += a.x * w0.z + a.y * w1.z + a.z * w2.z + a.w * w3.z;
            acc[r].w += a.x * w0.w + a.y * w1.w + a.z * w2.w + a.w * w3.w;
        }
    }

    float* pb = &part[(size_t)blockIdx.y * N_ * F];
    #pragma unroll
    for (int r = 0; r < 8; ++r)
        *(float4*)&pb[(size_t)(rg * 8 + r) * F + f0] = acc[r];
}

// K5: reduce 16 GEMM1 partials + b1, SiLU -> h[64][4096]
__global__ __launch_bounds__(256) void k_reduce_silu(
    const float* __restrict__ part, const float* __restrict__ b1,
    float* __restrict__ h)
{
    const int i = blockIdx.x * 256 + threadIdx.x;     // 262144
    float s = 0.f;
    #pragma unroll
    for (int p = 0; p < 16; ++p) s += part[(size_t)p * (N_ * FF_) + i];
    s += b1[i & (FF_ - 1)];
    h[i] = s / (1.f + expf(-s));                      // silu
}

// K7: reduce 64 GEMM2 partials + b2 -> y[64][1024]
__global__ __launch_bounds__(256) void k_reduce_bias(
    const float* __restrict__ part, const float* __restrict__ b2,
    float* __restrict__ y)
{
    const int i = blockIdx.x * 256 + threadIdx.x;     // 65536
    float s = 0.f;
    #pragma unroll
    for (int p = 0; p < 64; ++p) s += part[(size_t)p * (N_ * D_) + i];
    y[i] = s + b2[i & (D_ - 1)];
}

// ---------------------------------------------------------------------------
// K8: out[b][t][d] = sum_e softmax_e(logits[b,t,:])[e] * y[b*8+e][d]
// ---------------------------------------------------------------------------
__global__ __launch_bounds__(256) void k_combine(
    const float* __restrict__ logits, const float* __restrict__ y,
    float* __restrict__ out)
{
    __shared__ float wlds[64 * 8];
    const int tid = threadIdx.x;
    const int dc = blockIdx.x, tc = blockIdx.y, b = blockIdx.z;
    const int t0 = tc * 64;

    if (tid < 64) {
        const float* lp = &logits[((size_t)b * T_ + t0 + tid) * E_];
        float ex[8]; float s = 0.f;
        #pragma unroll
        for (int i = 0; i < 8; ++i) { ex[i] = expf(lp[i]); s += ex[i]; }
        const float invs = 1.f / s;
        #pragma unroll
        for (int i = 0; i < 8; ++i) wlds[tid * 8 + i] = ex[i] * invs;
    }
    __syncthreads();

    const int d = dc * 256 + tid;
    float yv[8];
    #pragma unroll
    for (int e = 0; e < 8; ++e) yv[e] = y[(size_t)(b * E_ + e) * D_ + d];

    for (int t = 0; t < 64; ++t) {
        const float4 wA = *(const float4*)&wlds[t * 8];
        const float4 wB = *(const float4*)&wlds[t * 8 + 4];
        const float acc = wA.x * yv[0] + wA.y * yv[1] + wA.z * yv[2] + wA.w * yv[3]
                        + wB.x * yv[4] + wB.y * yv[5] + wB.z * yv[6] + wB.w * yv[7];
        out[((size_t)b * T_ + t0 + t) * D_ + d] = acc;
    }
}

// ---------------------------------------------------------------------------
extern "C" void kernel_launch(void* const* d_in, const int* in_sizes, int n_in,
                              void* d_out, int out_size, void* d_ws, size_t ws_size,
                              hipStream_t stream)
{
    const float* X  = (const float*)d_in[0];
    const float* Wg = (const float*)d_in[1];
    const float* bg = (const float*)d_in[2];
    const float* W1 = (const float*)d_in[3];
    const float* b1 = (const float*)d_in[4];
    const float* W2 = (const float*)d_in[5];
    const float* b2 = (const float*)d_in[6];
    float* out = (float*)d_out;

    // ws layout (fp32), ~2.0 MB total
    float* wsf    = (float*)d_ws;
    float* logits = wsf;                        // 131072
    float* sumexp = logits + BT_ * E_;          // 64
    float* slots  = sumexp + 64;                // 65536
    float* h      = slots + N_ * D_;            // 262144
    float* y      = h + N_ * FF_;               // 65536

    // Large partial buffers live in d_out (64 MB), fully overwritten by
    // k_combine at the end. Max partial usage = 16 MB.
    float* part = out;

    hipMemsetAsync(sumexp, 0, 64 * sizeof(float), stream);

    hipLaunchKernelGGL(k_logits_part,  dim3(BT_ / 256, 8), dim3(256), 0, stream,
                       X, Wg, part);
    hipLaunchKernelGGL(k_logits_merge, dim3(BT_ / 256),    dim3(256), 0, stream,
                       part, bg, logits, sumexp);
    hipLaunchKernelGGL(k_slots_part,   dim3(64, 8),        dim3(256), 0, stream,
                       X, logits, sumexp, part);
    hipLaunchKernelGGL(k_reduce_slots, dim3(256),          dim3(256), 0, stream,
                       part, slots);
    hipLaunchKernelGGL(k_gemm_part,    dim3(FF_ / 128, 1024 / 64), dim3(256), 0, stream,
                       slots, W1, part, 1024, FF_);
    hipLaunchKernelGGL(k_reduce_silu,  dim3(N_ * FF_ / 256), dim3(256), 0, stream,
                       part, b1, h);
    hipLaunchKernelGGL(k_gemm_part,    dim3(D_ / 128, FF_ / 64), dim3(256), 0, stream,
                       h, W2, part, FF_, D_);
    hipLaunchKernelGGL(k_reduce_bias,  dim3(N_ * D_ / 256), dim3(256), 0, stream,
                       part, b2, y);
    hipLaunchKernelGGL(k_combine,      dim3(4, 32, 8), dim3(256), 0, stream,
                       logits, y, out);
}

// Round 3
// 251.338 us; speedup vs baseline: 1.2687x; 1.0361x over previous
//
#include <hip/hip_runtime.h>
#include <math.h>

#define B_  8
#define T_  2048
#define D_  1024
#define E_  8
#define FF_ 4096
#define N_  64            // B*E rows through the FFN
#define BT_ (B_*T_)

// ---------------------------------------------------------------------------
// K1a: partial logits over a 128-d chunk. grid (BT/256, 8), 256 threads.
// Thread owns ONE token, all 8 experts. X staged in LDS (coalesced);
// Wg read DIRECTLY from global with block-uniform addresses -> scalar
// s_load path (constant-cached, off the LDS pipe). part[dc][t][e].
// ---------------------------------------------------------------------------
__global__ __launch_bounds__(256) void k_logits_part(
    const float* __restrict__ X, const float* __restrict__ Wg,
    float* __restrict__ part)
{
    __shared__ float xt[256 * 36];       // 256 tokens x 32 d (pad 36), 36 KB

    const int tid = threadIdx.x;
    const int bt0 = blockIdx.x * 256;
    const int d0  = blockIdx.y * 128;

    float acc[8];
    #pragma unroll
    for (int e = 0; e < 8; ++e) acc[e] = 0.f;

    for (int dt = 0; dt < 4; ++dt) {
        if (dt) __syncthreads();          // WAR: previous compute vs restage
        #pragma unroll
        for (int r = 0; r < 8; ++r) {
            int fi = r * 256 + tid;       // float4 index = token*8 + dj
            int token = fi >> 3, dj = fi & 7;
            const float4 v = *(const float4*)
                &X[(size_t)(bt0 + token) * D_ + d0 + dt * 32 + dj * 4];
            *(float4*)&xt[token * 36 + dj * 4] = v;
        }
        __syncthreads();
        #pragma unroll
        for (int dj = 0; dj < 8; ++dj) {
            const float4 x4 = *(const float4*)&xt[tid * 36 + dj * 4];
            const int db = d0 + dt * 32 + dj * 4;      // block-uniform
            const float xv[4] = {x4.x, x4.y, x4.z, x4.w};
            #pragma unroll
            for (int r = 0; r < 4; ++r) {
                // 8 contiguous floats Wg[db+r][0..7]: uniform -> s_load
                const float4 wlo = *(const float4*)&Wg[(size_t)(db + r) * 8];
                const float4 whi = *(const float4*)&Wg[(size_t)(db + r) * 8 + 4];
                acc[0] += xv[r] * wlo.x; acc[1] += xv[r] * wlo.y;
                acc[2] += xv[r] * wlo.z; acc[3] += xv[r] * wlo.w;
                acc[4] += xv[r] * whi.x; acc[5] += xv[r] * whi.y;
                acc[6] += xv[r] * whi.z; acc[7] += xv[r] * whi.w;
            }
        }
    }

    float* pp = &part[(size_t)blockIdx.y * BT_ * E_ + (size_t)(bt0 + tid) * E_];
    *(float4*)&pp[0] = make_float4(acc[0], acc[1], acc[2], acc[3]);
    *(float4*)&pp[4] = make_float4(acc[4], acc[5], acc[6], acc[7]);
}

// ---------------------------------------------------------------------------
// K1b: merge 8 d-chunk partials + bg -> logits; per-block per-e sum of exp
// written to sexp_part[blk][8] (no atomics). grid (BT/256) = 64.
// ---------------------------------------------------------------------------
__global__ __launch_bounds__(256) void k_logits_merge(
    const float* __restrict__ part, const float* __restrict__ bg,
    float* __restrict__ logits, float* __restrict__ sexp_part)
{
    __shared__ float red[8 * 256];
    const int tid = threadIdx.x;
    const int token = blockIdx.x * 256 + tid;

    float a[8];
    #pragma unroll
    for (int e = 0; e < 8; ++e) a[e] = 0.f;
    #pragma unroll
    for (int p = 0; p < 8; ++p) {
        const float* pp = &part[(size_t)p * BT_ * E_ + (size_t)token * E_];
        const float4 v0 = *(const float4*)&pp[0];
        const float4 v1 = *(const float4*)&pp[4];
        a[0] += v0.x; a[1] += v0.y; a[2] += v0.z; a[3] += v0.w;
        a[4] += v1.x; a[5] += v1.y; a[6] += v1.z; a[7] += v1.w;
    }
    #pragma unroll
    for (int e = 0; e < 8; ++e) a[e] += bg[e];

    float* lp = &logits[(size_t)token * E_];
    *(float4*)&lp[0] = make_float4(a[0], a[1], a[2], a[3]);
    *(float4*)&lp[4] = make_float4(a[4], a[5], a[6], a[7]);

    #pragma unroll
    for (int e = 0; e < 8; ++e) red[e * 256 + tid] = expf(a[e]);
    __syncthreads();
    for (int s = 128; s >= 1; s >>= 1) {
        if (tid < s) {
            #pragma unroll
            for (int e = 0; e < 8; ++e)
                red[e * 256 + tid] += red[e * 256 + tid + s];
        }
        __syncthreads();
    }
    if (tid < 8) sexp_part[blockIdx.x * 8 + tid] = red[tid * 256];
}

// ---------------------------------------------------------------------------
// K2: slots partials. grid (32 slices of 64 tokens, 8 b), 256 threads.
// First reduces the 8 sexp_part blocks of this batch -> inv[8] in LDS.
// Thread owns one d-float4; unroll-8 t-loop keeps loads in flight.
// ---------------------------------------------------------------------------
__global__ __launch_bounds__(256) void k_slots_part(
    const float* __restrict__ X, const float* __restrict__ logits,
    const float* __restrict__ sexp_part, float* __restrict__ part)
{
    __shared__ float wlds[64 * 8];
    __shared__ float red[64];
    __shared__ float inv[8];

    const int tid = threadIdx.x;
    const int ts = blockIdx.x, b = blockIdx.y;
    const int t0 = ts * 64;

    if (tid < 64) red[tid] = sexp_part[b * 64 + tid];   // [i][e], i=blk-in-b
    __syncthreads();
    if (tid < 8) {
        float s = 0.f;
        #pragma unroll
        for (int i = 0; i < 8; ++i) s += red[i * 8 + tid];
        inv[tid] = 1.f / s;
    }
    __syncthreads();
    #pragma unroll
    for (int r = 0; r < 2; ++r) {
        int idx = r * 256 + tid;          // idx = t*8 + e over 64 tokens
        wlds[idx] = expf(logits[((size_t)b * T_ + t0) * E_ + idx]) * inv[idx & 7];
    }
    __syncthreads();

    float4 acc[8];
    #pragma unroll
    for (int e = 0; e < 8; ++e) { acc[e].x = acc[e].y = acc[e].z = acc[e].w = 0.f; }

    const float* xb = &X[((size_t)b * T_ + t0) * D_ + tid * 4];
    #pragma unroll 8
    for (int t = 0; t < 64; ++t) {
        const float4 x4 = *(const float4*)&xb[(size_t)t * D_];
        const float4 wA = *(const float4*)&wlds[t * 8];       // broadcast
        const float4 wB = *(const float4*)&wlds[t * 8 + 4];   // broadcast
        const float w[8] = {wA.x, wA.y, wA.z, wA.w, wB.x, wB.y, wB.z, wB.w};
        #pragma unroll
        for (int e = 0; e < 8; ++e) {
            acc[e].x += x4.x * w[e];
            acc[e].y += x4.y * w[e];
            acc[e].z += x4.z * w[e];
            acc[e].w += x4.w * w[e];
        }
    }
    #pragma unroll
    for (int e = 0; e < 8; ++e) {
        *(float4*)&part[(size_t)ts * (N_ * D_) + (size_t)(b * E_ + e) * D_ + tid * 4] = acc[e];
    }
}

// K3: reduce 32 slot partials -> slots[64][1024]
__global__ __launch_bounds__(256) void k_reduce_slots(
    const float* __restrict__ part, float* __restrict__ slots)
{
    const int i = blockIdx.x * 256 + threadIdx.x;     // 65536
    float s = 0.f;
    #pragma unroll
    for (int p = 0; p < 32; ++p) s += part[(size_t)p * (N_ * D_) + i];
    slots[i] = s;
}

// ---------------------------------------------------------------------------
// K4/K6: k-split GEMM partial, KT=128. part[kc][n][f] = sum_k A[n][k]*W[k][f].
// Block tile 64 rows x 128 cols, 256 threads: thread = (rg = tid>>5 owning
// 8 rows, cg = tid&31 owning 4 cols). acc = 8 x float4 = 32 VGPR (no spill).
// A staged [row][kk]; inner A-reads are half-wave broadcasts, W coalesced.
// grid (F/128, K/128).
// ---------------------------------------------------------------------------
__global__ __launch_bounds__(256) void k_gemm_part(
    const float* __restrict__ A, const float* __restrict__ W,
    float* __restrict__ part, int K, int F)
{
    __shared__ float As[64][128];                 // 32 KB, [row][kk]

    const int tid = threadIdx.x;
    const int rg  = tid >> 5;                     // 0..7  (8 rows each)
    const int cg  = tid & 31;                     // 0..31 (4 cols each)
    const int f0  = blockIdx.x * 128 + cg * 4;
    const int k0  = blockIdx.y * 128;

    // stage A tile: 64 rows x 128 kk = 2048 float4, 8 per thread, coalesced.
    #pragma unroll
    for (int i = 0; i < 8; ++i) {
        int idx = i * 256 + tid;                  // row = idx>>5, kq = idx&31
        int row = idx >> 5, kq = idx & 31;
        const float4 v = *(const float4*)&A[(size_t)row * K + k0 + kq * 4];
        *(float4*)&As[row][kq * 4] = v;
    }
    __syncthreads();

    float4 acc[8];
    #pragma unroll
    for (int r = 0; r < 8; ++r) { acc[r].x = acc[r].y = acc[r].z = acc[r].w = 0.f; }

    #pragma unroll 2
    for (int kq = 0; kq < 32; ++kq) {             // 4 kk per step
        float4 w0 = *(const float4*)&W[(size_t)(k0 + kq * 4 + 0) * F + f0];
        float4 w1 = *(const float4*)&W[(size_t)(k0 + kq * 4 + 1) * F + f0];
        float4 w2 = *(const float4*)&W[(size_t)(k0 + kq * 4 + 2) * F + f0];
        float4 w3 = *(const float4*)&W[(size_t)(k0 + kq * 4 + 3) * F + f0];
        #pragma unroll
        for (int r = 0; r < 8; ++r) {
            const float4 a = *(const float4*)&As[rg * 8 + r][kq * 4];  // broadcast
            acc[r].x += a.x * w0.x + a.y * w1.x + a.z * w2.x + a.w * w3.x;
            acc[r].y += a.x * w0.y + a.y * w1.y + a.z * w2.y + a.w * w3.y;
            acc[r].z += a.x * w0.z + a.y * w1.z + a.z * w2.z + a.w * w3.z;
            acc[r].w += a.x * w0.w + a.y * w1.w + a.z * w2.w + a.w * w3.w;
        }
    }

    float* pb = &part[(size_t)blockIdx.y * N_ * F];
    #pragma unroll
    for (int r = 0; r < 8; ++r)
        *(float4*)&pb[(size_t)(rg * 8 + r) * F + f0] = acc[r];
}

// K5: reduce 8 GEMM1 partials + b1, SiLU -> h[64][4096]
__global__ __launch_bounds__(256) void k_reduce_silu(
    const float* __restrict__ part, const float* __restrict__ b1,
    float* __restrict__ h)
{
    const int i = blockIdx.x * 256 + threadIdx.x;     // 262144
    float s = 0.f;
    #pragma unroll
    for (int p = 0; p < 8; ++p) s += part[(size_t)p * (N_ * FF_) + i];
    s += b1[i & (FF_ - 1)];
    h[i] = s / (1.f + expf(-s));                      // silu
}

// K7: reduce 32 GEMM2 partials + b2 -> y[64][1024]
__global__ __launch_bounds__(256) void k_reduce_bias(
    const float* __restrict__ part, const float* __restrict__ b2,
    float* __restrict__ y)
{
    const int i = blockIdx.x * 256 + threadIdx.x;     // 65536
    float s = 0.f;
    #pragma unroll
    for (int p = 0; p < 32; ++p) s += part[(size_t)p * (N_ * D_) + i];
    y[i] = s + b2[i & (D_ - 1)];
}

// ---------------------------------------------------------------------------
// K8: out[b][t][d] = sum_e softmax_e(logits[b,t,:])[e] * y[b*8+e][d]
// ---------------------------------------------------------------------------
__global__ __launch_bounds__(256) void k_combine(
    const float* __restrict__ logits, const float* __restrict__ y,
    float* __restrict__ out)
{
    __shared__ float wlds[64 * 8];
    const int tid = threadIdx.x;
    const int dc = blockIdx.x, tc = blockIdx.y, b = blockIdx.z;
    const int t0 = tc * 64;

    if (tid < 64) {
        const float* lp = &logits[((size_t)b * T_ + t0 + tid) * E_];
        float ex[8]; float s = 0.f;
        #pragma unroll
        for (int i = 0; i < 8; ++i) { ex[i] = expf(lp[i]); s += ex[i]; }
        const float invs = 1.f / s;
        #pragma unroll
        for (int i = 0; i < 8; ++i) wlds[tid * 8 + i] = ex[i] * invs;
    }
    __syncthreads();

    const int d = dc * 256 + tid;
    float yv[8];
    #pragma unroll
    for (int e = 0; e < 8; ++e) yv[e] = y[(size_t)(b * E_ + e) * D_ + d];

    for (int t = 0; t < 64; ++t) {
        const float4 wA = *(const float4*)&wlds[t * 8];
        const float4 wB = *(const float4*)&wlds[t * 8 + 4];
        const float acc = wA.x * yv[0] + wA.y * yv[1] + wA.z * yv[2] + wA.w * yv[3]
                        + wB.x * yv[4] + wB.y * yv[5] + wB.z * yv[6] + wB.w * yv[7];
        out[((size_t)b * T_ + t0 + t) * D_ + d] = acc;
    }
}

// ---------------------------------------------------------------------------
extern "C" void kernel_launch(void* const* d_in, const int* in_sizes, int n_in,
                              void* d_out, int out_size, void* d_ws, size_t ws_size,
                              hipStream_t stream)
{
    const float* X  = (const float*)d_in[0];
    const float* Wg = (const float*)d_in[1];
    const float* bg = (const float*)d_in[2];
    const float* W1 = (const float*)d_in[3];
    const float* b1 = (const float*)d_in[4];
    const float* W2 = (const float*)d_in[5];
    const float* b2 = (const float*)d_in[6];
    float* out = (float*)d_out;

    // ws layout (fp32), ~1.9 MB total
    float* wsf       = (float*)d_ws;
    float* logits    = wsf;                        // 131072
    float* sexp_part = logits + BT_ * E_;          // 512 (64 blocks x 8 e)
    float* slots     = sexp_part + 512;            // 65536
    float* h         = slots + N_ * D_;            // 262144
    float* y         = h + N_ * FF_;               // 65536

    // Large partial buffers live in d_out (64 MB), fully overwritten by
    // k_combine at the end. Max partial usage = 8 MB.
    float* part = out;

    hipLaunchKernelGGL(k_logits_part,  dim3(BT_ / 256, 8), dim3(256), 0, stream,
                       X, Wg, part);
    hipLaunchKernelGGL(k_logits_merge, dim3(BT_ / 256),    dim3(256), 0, stream,
                       part, bg, logits, sexp_part);
    hipLaunchKernelGGL(k_slots_part,   dim3(32, 8),        dim3(256), 0, stream,
                       X, logits, sexp_part, part);
    hipLaunchKernelGGL(k_reduce_slots, dim3(256),          dim3(256), 0, stream,
                       part, slots);
    hipLaunchKernelGGL(k_gemm_part,    dim3(FF_ / 128, 1024 / 128), dim3(256), 0, stream,
                       slots, W1, part, 1024, FF_);
    hipLaunchKernelGGL(k_reduce_silu,  dim3(N_ * FF_ / 256), dim3(256), 0, stream,
                       part, b1, h);
    hipLaunchKernelGGL(k_gemm_part,    dim3(D_ / 128, FF_ / 128), dim3(256), 0, stream,
                       h, W2, part, FF_, D_);
    hipLaunchKernelGGL(k_reduce_bias,  dim3(N_ * D_ / 256), dim3(256), 0, stream,
                       part, b2, y);
    hipLaunchKernelGGL(k_combine,      dim3(4, 32, 8), dim3(256), 0, stream,
                       logits, y, out);
}